// Round 5
// baseline (244.621 us; speedup 1.0000x reference)
//
#include <hip/hip_runtime.h>
#include <math.h>

#define NENTITY   100000
#define NRELATION 500
#define HID       100
#define HOUSE_DIM 4
#define HOUSE_NUM 10
#define B_SZ      512
#define NEG       256
#define THRED     0.5f
#define GAMMA     12.0f

#define SEGS           4                    // main blocks per batch row
#define NEG_PER_BLOCK  (NEG / SEGS)         // 64
#define BLOCK          256                  // 4 waves
#define NEG_PER_WAVE   (NEG_PER_BLOCK / 4)  // 16

// d_ws layout (floats):
//   wsHead : float4[B_SZ][HID]   offset 0
//   wsV0   : float4[B_SZ][HID]   offset 1*B_SZ*HID*4
//   wsV1   : float4[B_SZ][HID]   offset 2*B_SZ*HID*4
//   wsKt   : float2[B_SZ][HID]   offset 3*B_SZ*HID*4
#define WS_F4_STRIDE (B_SZ * HID)

__device__ __forceinline__ float dot4(const float4 a, const float4 b) {
    return a.x * b.x + a.y * b.y + a.z * b.z + a.w * b.w;
}

__device__ __forceinline__ float4 norm4(float4 v) {
    const float n = fmaxf(sqrtf(dot4(v, v)), 1e-12f);
    const float inv = 1.0f / n;
    v.x *= inv; v.y *= inv; v.z *= inv; v.w *= inv;
    return v;
}

__device__ __forceinline__ float4 reflect4(float4 x, const float4 v, const float coef) {
    const float s = coef * dot4(v, x);
    x.x -= s * v.x; x.y -= s * v.y; x.z -= s * v.z; x.w -= s * v.w;
    return x;
}

// two tail reflections then ||hd - tv||
__device__ __forceinline__ float hdist(float4 tv, const float4 v0, const float4 v1,
                                       const float2 kt, const float4 hd) {
    const float s0 = kt.x * dot4(v0, tv);
    tv.x -= s0 * v0.x; tv.y -= s0 * v0.y; tv.z -= s0 * v0.z; tv.w -= s0 * v0.w;
    const float s1 = kt.y * dot4(v1, tv);
    tv.x -= s1 * v1.x; tv.y -= s1 * v1.y; tv.z -= s1 * v1.z; tv.w -= s1 * v1.w;
    const float dx = hd.x - tv.x;
    const float dy = hd.y - tv.y;
    const float dz = hd.z - tv.z;
    const float dw = hd.w - tv.w;
    return sqrtf(dx * dx + dy * dy + dz * dz + dw * dw);
}

// ---- Kernel A: per-(b,hid) prep, once per batch row ----
__global__ __launch_bounds__(128) void house_prep_kernel(
    const float* __restrict__ ent,
    const float* __restrict__ rel,
    const float* __restrict__ kdh,
    const float* __restrict__ kdt,
    const float* __restrict__ ksh,
    const float* __restrict__ kst,
    const int* __restrict__ head_idx,
    const int* __restrict__ rel_idx,
    float* __restrict__ ws)
{
    const int b = blockIdx.x;
    const int h = threadIdx.x;
    if (h >= HID) return;
    const int r = rel_idx[b];

    const float4* rr = (const float4*)(rel + ((size_t)r * HID + h) * (HOUSE_NUM * HOUSE_DIM));

    const int he = head_idx[b];
    float4 hd = ((const float4*)ent)[(size_t)he * HID + h];

    const float kh0 = fminf(kdh[r * 2 + 0] * fabsf(ksh[((size_t)r * HID + h) * 2 + 0]), THRED);
    const float kh1 = fminf(kdh[r * 2 + 1] * fabsf(ksh[((size_t)r * HID + h) * 2 + 1]), THRED);

    hd = reflect4(hd, norm4(rr[9]), kh0);
    hd = reflect4(hd, norm4(rr[8]), kh1);
    #pragma unroll
    for (int j = 7; j >= 2; --j) hd = reflect4(hd, norm4(rr[j]), 2.0f);

    const float kt0 = fminf(kdt[r * 2 + 0] * fabsf(kst[((size_t)r * HID + h) * 2 + 0]), THRED);
    const float kt1 = fminf(kdt[r * 2 + 1] * fabsf(kst[((size_t)r * HID + h) * 2 + 1]), THRED);

    float4* wsHead = (float4*)ws;
    float4* wsV0   = wsHead + WS_F4_STRIDE;
    float4* wsV1   = wsV0 + WS_F4_STRIDE;
    float2* wsKt   = (float2*)(wsV1 + WS_F4_STRIDE);

    const int idx = b * HID + h;
    wsHead[idx] = hd;
    wsV0[idx]   = norm4(rr[0]);
    wsV1[idx]   = norm4(rr[1]);
    wsKt[idx]   = make_float2(kt0, kt1);
}

// ---- Kernel B: cooperative gather + score. No LDS, no barrier. ----
__global__ __launch_bounds__(BLOCK, 8) void house_score_kernel(
    const float* __restrict__ ent,
    const int* __restrict__ tail_idx,
    const float* __restrict__ ws,
    float* __restrict__ out)
{
    const int blk = blockIdx.x;
    const int b   = blk >> 2;          // SEGS = 4
    const int seg = blk & (SEGS - 1);
    const int tid = threadIdx.x;
    const int w = tid >> 6;   // wave in block
    const int l = tid & 63;   // lane

    const float4* wsHead = (const float4*)ws;
    const float4* wsV0   = wsHead + WS_F4_STRIDE;
    const float4* wsV1   = wsV0 + WS_F4_STRIDE;
    const float2* wsKt   = (const float2*)(wsV1 + WS_F4_STRIDE);

    // lane l owns hids {l, 64+l (l<36)}
    const int i1 = b * HID + l;
    const float4 hd1 = wsHead[i1];
    const float4 v01 = wsV0[i1];
    const float4 v11 = wsV1[i1];
    const float2 k1  = wsKt[i1];
    const int   l2   = (l < 36) ? (64 + l) : 99;  // clamped, inactive lanes read idx 99
    const int   i2   = b * HID + l2;
    const float4 hd2 = wsHead[i2];
    const float4 v02 = wsV0[i2];
    const float4 v12 = wsV1[i2];
    const float2 k2  = wsKt[i2];
    const bool has2  = (l < 36);

    const int negbase = seg * NEG_PER_BLOCK + w * NEG_PER_WAVE;

    // this wave's 16 tail indices live in lanes 0..15
    int my_e = 0;
    if (l < NEG_PER_WAVE) my_e = tail_idx[(size_t)b * NEG + negbase + l];

    const float4* entf4 = (const float4*)ent;

    #pragma unroll 4
    for (int i = 0; i < NEG_PER_WAVE; ++i) {
        const int e = __shfl(my_e, i);
        const float4* row = entf4 + (size_t)e * HID;

        const float4 t1 = row[l];                       // bytes 0..1023
        float d2 = 0.0f;
        if (has2) {
            const float4 t2 = row[64 + l];              // bytes 1024..1599
            d2 = hdist(t2, v02, v12, k2, hd2);
        }
        float s = hdist(t1, v01, v11, k1, hd1) + d2;

        #pragma unroll
        for (int m = 1; m < 64; m <<= 1) s += __shfl_xor(s, m);

        if (l == 0) out[(size_t)b * NEG + negbase + i] = GAMMA - s;
    }
}

extern "C" void kernel_launch(void* const* d_in, const int* in_sizes, int n_in,
                              void* d_out, int out_size, void* d_ws, size_t ws_size,
                              hipStream_t stream) {
    const float* ent = (const float*)d_in[0];
    const float* rel = (const float*)d_in[1];
    const float* kdh = (const float*)d_in[2];
    const float* kdt = (const float*)d_in[3];
    const float* ksh = (const float*)d_in[4];
    const float* kst = (const float*)d_in[5];
    const int* head_idx = (const int*)d_in[6];
    const int* rel_idx  = (const int*)d_in[7];
    const int* tail_idx = (const int*)d_in[8];
    float* out = (float*)d_out;
    float* ws  = (float*)d_ws;

    house_prep_kernel<<<B_SZ, 128, 0, stream>>>(
        ent, rel, kdh, kdt, ksh, kst, head_idx, rel_idx, ws);
    house_score_kernel<<<B_SZ * SEGS, BLOCK, 0, stream>>>(
        ent, tail_idx, ws, out);
}